// Round 6
// baseline (374.301 us; speedup 1.0000x reference)
//
#include <hip/hip_runtime.h>
#include <hip/hip_bf16.h>

typedef __bf16 bf16x8 __attribute__((ext_vector_type(8)));
typedef __bf16 bf16x4 __attribute__((ext_vector_type(4)));
typedef float  f32x4  __attribute__((ext_vector_type(4)));
typedef float  f32x16 __attribute__((ext_vector_type(16)));

#define B_    64
#define CIN   64
#define HIN   64
#define WIN   64
#define COUT  128
#define HO    62
#define WO    62
#define NPIX  (B_*HO*WO)        /* 246016 = 3844*64 exactly */
#define NITER 10                /* fused rounds; +1 final matvec = 11 total */
#define NPERS 3                 /* m-tiles 0..2 persist in AGPR (12 frags)  */

// Register-file steering on the gfx950 unified VGPR/AGPR file.
#define PIN_A(x) asm volatile("" : "+a"(x))
#define PIN_V(x) asm volatile("" : "+v"(x))

// relu + packed f32->bf16 convert: word w = [bf16(lo), bf16(hi)] (RNE).
__device__ __forceinline__ bf16x8 relu_pack_pair(f32x4 a0, f32x4 a1) {
  union { unsigned int w[4]; bf16x8 v; } u;
  float l0 = fmaxf(a0[0], 0.f), l1 = fmaxf(a0[1], 0.f);
  float l2 = fmaxf(a0[2], 0.f), l3 = fmaxf(a0[3], 0.f);
  float h0 = fmaxf(a1[0], 0.f), h1 = fmaxf(a1[1], 0.f);
  float h2 = fmaxf(a1[2], 0.f), h3 = fmaxf(a1[3], 0.f);
  asm("v_cvt_pk_bf16_f32 %0, %1, %2" : "=v"(u.w[0]) : "v"(l0), "v"(l1));
  asm("v_cvt_pk_bf16_f32 %0, %1, %2" : "=v"(u.w[1]) : "v"(l2), "v"(l3));
  asm("v_cvt_pk_bf16_f32 %0, %1, %2" : "=v"(u.w[2]) : "v"(h0), "v"(h1));
  asm("v_cvt_pk_bf16_f32 %0, %1, %2" : "=v"(u.w[3]) : "v"(h2), "v"(h3));
  return u.v;
}

// ---------------------------------------------------------------------------
// prep_w: W_ff -> wt[tap][o][c] bf16 ;
//         W_rec -> wrp: NEGATED, pre-permuted per-lane A-fragment table.
// wrp[((mt*4+kt)*64 + lane)*8 + e] = -wrec[m][ch],
//   m  = mt*16 + (lane&15)
//   ch = kt*16 + 64*(e>>2) + (lane>>4)*4 + (e&3)   (k-slot permutation)
// ---------------------------------------------------------------------------
__global__ void prep_w_kernel(const float* __restrict__ wff,
                              const float* __restrict__ wrec,
                              __bf16* __restrict__ wt,
                              __bf16* __restrict__ wrp) {
  int i = blockIdx.x * 256 + threadIdx.x;
  const int NW = 9 * COUT * CIN;            // 73728
  if (i < NW) {
    int tap = i / (COUT * CIN);
    int rem = i % (COUT * CIN);
    int o = rem >> 6;
    int c = rem & 63;
    int kh = tap / 3, kw = tap % 3;
    wt[i] = (__bf16)wff[((o * CIN + c) * 3 + kh) * 3 + kw];
  } else {
    int j = i - NW;                         // 0..16383
    if (j < 32 * 64 * 8) {
      int e    = j & 7;
      int lane = (j >> 3) & 63;
      int fk   = j >> 9;                    // mt*4 + kt
      int mt = fk >> 2, kt = fk & 3;
      int m    = mt * 16 + (lane & 15);
      int quad = lane >> 4;
      int ch   = kt * 16 + ((e >> 2) << 6) + quad * 4 + (e & 3);
      wrp[j] = (__bf16)(-wrec[m * COUT + ch]);
    }
  }
}

// ---------------------------------------------------------------------------
// prep_x: x NCHW fp32 -> bf16, layout [b][h][c>>3][w][c&7]
// ---------------------------------------------------------------------------
__global__ void prep_x_kernel(const float* __restrict__ x,
                              __bf16* __restrict__ xh) {
  __shared__ float t[64][65];
  int tid = threadIdx.x;
  int b = blockIdx.x >> 6;
  int h = blockIdx.x & 63;
#pragma unroll
  for (int it = 0; it < 16; ++it) {
    int c = it * 4 + (tid >> 6);
    int w = tid & 63;
    t[c][w] = x[(((size_t)(b * 64 + c)) * 64 + h) * 64 + w];
  }
  __syncthreads();
  size_t rowbase = (size_t)blockIdx.x * 4096;
#pragma unroll
  for (int it = 0; it < 16; ++it) {
    int j = it * 256 + tid;
    int c8  = j & 7;
    int w   = (j >> 3) & 63;
    int grp = j >> 9;
    xh[rowbase + j] = (__bf16)t[grp * 8 + c8][w];
  }
}

// ---------------------------------------------------------------------------
// conv: persistent-weight implicit GEMM, 32x32x16 bf16 MFMA.
// Wf (144 regs) pinned into AGPRs -> zero weight traffic in the nt loop.
// ---------------------------------------------------------------------------
__global__ __launch_bounds__(256, 2) void conv_kernel(
    const __bf16* __restrict__ xh, const __bf16* __restrict__ wt,
    float* __restrict__ u0) {
  // layout [row 6][grp 8][w 64][c8 8] = 24576 el = 48KB, flat == global order
  __shared__ __align__(16) __bf16 xs[6 * 8 * 64 * 8];
  int tid  = threadIdx.x;
  int lane = tid & 63;
  int wv   = tid >> 6;                      // 0..3 : c_out slice
  int hg   = blockIdx.x;                    // 0..15 : output-row group (4 rows)
  int b    = blockIdx.y;

  // ---- stage 6 input rows (hg*4 .. hg*4+5, clamped) ----
#pragma unroll
  for (int i = 0; i < 12; ++i) {
    int chunk = wv * 12 + i;                // 0..47
    int row = chunk >> 3;
    int part = chunk & 7;
    int row_src = hg * 4 + row;
    if (row_src > 63) row_src = 63;
    const __bf16* g = xh + ((size_t)(b * 64 + row_src)) * 4096 + part * 512 + lane * 8;
    __bf16* l = xs + chunk * 512;
    __builtin_amdgcn_global_load_lds(
        (const __attribute__((address_space(1))) void*)g,
        (__attribute__((address_space(3))) void*)l, 16, 0, 0);
  }

  // ---- this wave's full weight set -> AGPRs (loaded once, resident) ----
  int m31 = lane & 31;
  int khalf = lane >> 5;                    // A[m][k]: m=lane&31, k=khalf*8+j
  bf16x8 Wf[36];
#pragma unroll
  for (int tap = 0; tap < 9; ++tap)
#pragma unroll
    for (int k4 = 0; k4 < 4; ++k4)
      Wf[tap * 4 + k4] = *(const bf16x8*)
          &wt[((size_t)tap * COUT + wv * 32 + m31) * CIN + k4 * 16 + khalf * 8];
#pragma unroll
  for (int i = 0; i < 36; ++i) PIN_A(Wf[i]);

  __syncthreads();

  // ---- 8 n-tiles of 32 pixels ----
#pragma unroll 1
  for (int nt = 0; nt < 8; ++nt) {
    int px = nt * 32 + m31;                 // local pixel 0..255 (248 valid)
    int r = (px >= 62) + (px >= 124) + (px >= 186) + (px >= 248);
    if (r > 3) r = 3;
    int wcol = px - r * 62;
    if (wcol > 61) wcol = 61;
    int orow = hg * 4 + r;
    bool valid = (px < 248) && (orow < 62);
    const char* lbase = (const char*)xs + (((r * 8 + khalf) * 64 + wcol) << 4);

    f32x16 acc0, acc1;
#pragma unroll
    for (int q = 0; q < 16; ++q) { acc0[q] = 0.f; acc1[q] = 0.f; }

#pragma unroll
    for (int tap = 0; tap < 9; ++tap) {
      int kh = tap / 3, kw = tap % 3;
#pragma unroll
      for (int k4 = 0; k4 < 4; ++k4) {
        bf16x8 Bf = *(const bf16x8*)(lbase + kh * 8192 + k4 * 2048 + kw * 16);
        int idx = tap * 4 + k4;
        if (idx & 1) acc1 = __builtin_amdgcn_mfma_f32_32x32x16_bf16(Wf[idx], Bf, acc1, 0, 0, 0);
        else         acc0 = __builtin_amdgcn_mfma_f32_32x32x16_bf16(Wf[idx], Bf, acc0, 0, 0, 0);
      }
    }
    if (valid) {
      size_t pix = ((size_t)b * HO + orow) * WO + wcol;
      // C/D layout 32x32: col=lane&31, row=(reg&3)+8*(reg>>2)+4*khalf
      float* up = u0 + pix * COUT + wv * 32 + khalf * 4;
#pragma unroll
      for (int g4 = 0; g4 < 4; ++g4) {
        f32x4 v;
#pragma unroll
        for (int q = 0; q < 4; ++q) v[q] = acc0[g4 * 4 + q] + acc1[g4 * 4 + q];
        *(f32x4*)&up[g4 * 8] = v;
      }
    }
  }
}

// ---------------------------------------------------------------------------
// iterate: 11 undamped Picard matvecs. N=16 px/wave, 3 waves/SIMD.
// R5 post-mortem: R4 (N=16, 3 waves) was LDS-BW-bound at ~95 B/cyc/CU (the
// measured ds_read_b128 ceiling); R5's N=32 halved LDS/px but dropped to
// 2 waves/SIMD -> latency-bound, worse. This version keeps 3 waves and cuts
// LDS traffic instead:
//  (1) FUSED repack: compute m-tile pairs (kt2, kt2+4); Bf_next[kt2] is
//      packed immediately from the two fresh C-frags -> no persistent f32
//      acc array (saves 32 AGPR). Carrier across iterations = bf16 Bc[4].
//  (2) Freed AGPRs hold 12/32 A-frags persistently (mt 0..2); only 20
//      frags stream from LDS per iter (20 KB staged) -> LDS traffic x0.625.
//  (3) v_cvt_pk_bf16_f32 packs the relu'd outputs 2-per-instr (VALU was
//      57% busy in R4 and becomes co-binder after (2)).
// Ledger: AGPR = Afp 48 + u0f 32 + a0/a1 8 = 88; arch = Bc 16 + Bn 16 +
// stream/addr ~28 = ~60; total ~150 of 168 @ (256,3). Spill tripwire:
// FETCH >> 100 MB next round.
// ---------------------------------------------------------------------------
__global__ __launch_bounds__(256, 3) void iterate_kernel(
    const float* __restrict__ u0, const __bf16* __restrict__ wrp,
    const float* __restrict__ thr, float* __restrict__ out) {
  __shared__ __align__(16) __bf16 wrl[20 * 64 * 8];   // frags fk=12..31, 20 KB
  int tid = threadIdx.x;
  int lane = tid & 63, wv = tid >> 6;
  int l15 = lane & 15, quad = lane >> 4;
  size_t p = (size_t)blockIdx.x * 64 + wv * 16 + l15; // this lane's pixel
  int pb = (int)(p / (HO * WO));            // batch  (for NCHW store)
  int pr = (int)(p % (HO * WO));            // h*62+w

  // ---- stage stream frags (fk 12..31) -> LDS, 5 x 16B per thread ----
#pragma unroll
  for (int i = 0; i < 5; ++i) {
    const __bf16* g = wrp + (size_t)12 * 512 + (size_t)(i * 256 + tid) * 8;
    __bf16* l = wrl + (i * 256 + tid) * 8;
    __builtin_amdgcn_global_load_lds(
        (const __attribute__((address_space(1))) void*)g,
        (__attribute__((address_space(3))) void*)l, 16, 0, 0);
  }

  // ---- persistent A-frags fk 0..11 (mt 0..2) -> AGPR ----
  bf16x8 Afp[12];
#pragma unroll
  for (int j = 0; j < 12; ++j)
    Afp[j] = *(const bf16x8*)&wrp[((size_t)j * 64 + lane) * 8];
#pragma unroll
  for (int j = 0; j < 12; ++j) PIN_A(Afp[j]);

  // ---- u0 - thr fragments (C-layout) -> AGPR ----
  f32x4 u0f[8];
#pragma unroll
  for (int mt = 0; mt < 8; ++mt) {
    f32x4 u = *(const f32x4*)&u0[p * COUT + mt * 16 + quad * 4];
    f32x4 t = *(const f32x4*)&thr[mt * 16 + quad * 4];
    u0f[mt] = u - t;
  }
#pragma unroll
  for (int mt = 0; mt < 8; ++mt) PIN_A(u0f[mt]);

  // initial activations: Bc[kt] = pack(relu(u0f[kt]), relu(u0f[kt+4]))
  bf16x8 Bc[4];
#pragma unroll
  for (int kt = 0; kt < 4; ++kt) Bc[kt] = relu_pack_pair(u0f[kt], u0f[kt + 4]);

  __syncthreads();                          // wrl ready (vmcnt drained here)

  const __bf16* afrag = &wrl[(size_t)lane * 8];   // + (fk-12)*1024B imm

#pragma unroll 1
  for (int it = 0; it < NITER; ++it) {
    bf16x8 Bn[4];
#pragma unroll
    for (int kt2 = 0; kt2 < 4; ++kt2) {
      f32x4 a0 = u0f[kt2];                  // mt = kt2   (persist if < 3)
      f32x4 a1 = u0f[kt2 + 4];              // mt = kt2+4 (streamed)
#pragma unroll
      for (int kt = 0; kt < 4; ++kt) {
        bf16x8 A1 = *(const bf16x8*)(afrag + (size_t)((kt2 + 4) * 4 + kt - 12) * 512);
        if (kt2 < NPERS) {
          a0 = __builtin_amdgcn_mfma_f32_16x16x32_bf16(Afp[kt2 * 4 + kt], Bc[kt], a0, 0, 0, 0);
        } else {
          bf16x8 A0 = *(const bf16x8*)(afrag + (size_t)(kt2 * 4 + kt - 12) * 512);
          a0 = __builtin_amdgcn_mfma_f32_16x16x32_bf16(A0, Bc[kt], a0, 0, 0, 0);
        }
        a1 = __builtin_amdgcn_mfma_f32_16x16x32_bf16(A1, Bc[kt], a1, 0, 0, 0);
      }
      Bn[kt2] = relu_pack_pair(a0, a1);     // Bf slot kt2 <- m-tiles kt2,kt2+4
    }
#pragma unroll
    for (int kt = 0; kt < 4; ++kt) Bc[kt] = Bn[kt];
  }

  // final matvec -> relu -> NCHW global store (same pair structure)
#pragma unroll
  for (int kt2 = 0; kt2 < 4; ++kt2) {
    f32x4 a0 = u0f[kt2];
    f32x4 a1 = u0f[kt2 + 4];
#pragma unroll
    for (int kt = 0; kt < 4; ++kt) {
      bf16x8 A1 = *(const bf16x8*)(afrag + (size_t)((kt2 + 4) * 4 + kt - 12) * 512);
      if (kt2 < NPERS) {
        a0 = __builtin_amdgcn_mfma_f32_16x16x32_bf16(Afp[kt2 * 4 + kt], Bc[kt], a0, 0, 0, 0);
      } else {
        bf16x8 A0 = *(const bf16x8*)(afrag + (size_t)(kt2 * 4 + kt - 12) * 512);
        a0 = __builtin_amdgcn_mfma_f32_16x16x32_bf16(A0, Bc[kt], a0, 0, 0, 0);
      }
      a1 = __builtin_amdgcn_mfma_f32_16x16x32_bf16(A1, Bc[kt], a1, 0, 0, 0);
    }
#pragma unroll
    for (int r = 0; r < 4; ++r) {
      int ch0 = kt2 * 16 + quad * 4 + r;
      int ch1 = (kt2 + 4) * 16 + quad * 4 + r;
      out[((size_t)pb * COUT + ch0) * (HO * WO) + pr] = fmaxf(a0[r], 0.f);
      out[((size_t)pb * COUT + ch1) * (HO * WO) + pr] = fmaxf(a1[r], 0.f);
    }
  }
}

// ---------------------------------------------------------------------------
extern "C" void kernel_launch(void* const* d_in, const int* in_sizes, int n_in,
                              void* d_out, int out_size, void* d_ws, size_t ws_size,
                              hipStream_t stream) {
  const float* x    = (const float*)d_in[0];   // (64,64,64,64)
  const float* wff  = (const float*)d_in[1];   // (128,64,3,3)
  const float* wrec = (const float*)d_in[2];   // (128,128,1,1)
  const float* thr  = (const float*)d_in[3];   // (128,)
  float* out = (float*)d_out;                  // (64,128,62,62)

  char* ws = (char*)d_ws;
  size_t off = 0;
  float*  u0 = (float*)(ws + off);  off += (size_t)NPIX * COUT * 4;          // 126 MB
  __bf16* xh = (__bf16*)(ws + off); off += (size_t)B_ * HIN * WIN * CIN * 2; // 33.6 MB
  __bf16* wt = (__bf16*)(ws + off); off += (size_t)9 * COUT * CIN * 2;       // 147 KB
  __bf16* wrp = (__bf16*)(ws + off); off += (size_t)32 * 64 * 8 * 2;         // 32 KB

  prep_w_kernel<<<352, 256, 0, stream>>>(wff, wrec, wt, wrp);
  prep_x_kernel<<<B_ * HIN, 256, 0, stream>>>(x, xh);
  conv_kernel<<<dim3(16, B_), 256, 0, stream>>>(xh, wt, u0);
  iterate_kernel<<<NPIX / 64, 256, 0, stream>>>(u0, wrp, thr, out);
}

// Round 7
// 324.850 us; speedup vs baseline: 1.1522x; 1.1522x over previous
//
#include <hip/hip_runtime.h>
#include <hip/hip_bf16.h>

typedef __bf16 bf16x8 __attribute__((ext_vector_type(8)));
typedef __bf16 bf16x4 __attribute__((ext_vector_type(4)));
typedef float  f32x4  __attribute__((ext_vector_type(4)));
typedef float  f32x16 __attribute__((ext_vector_type(16)));

#define B_    64
#define CIN   64
#define HIN   64
#define WIN   64
#define COUT  128
#define HO    62
#define WO    62
#define NPIX  (B_*HO*WO)        /* 246016 = 3844*64 exactly */
#define NITER 10                /* LDS rounds; +1 final matvec = 11 total */

// Register-file steering on the gfx950 unified VGPR/AGPR file.
#define PIN_A(x) asm volatile("" : "+a"(x))
#define PIN_V(x) asm volatile("" : "+v"(x))

// ---------------------------------------------------------------------------
// prep_w: W_ff -> wt[tap][o][c] bf16 ;
//         W_rec -> wrp: NEGATED, pre-permuted per-lane A-fragment table.
// wrp[((mt*4+kt)*64 + lane)*8 + e] = -wrec[m][ch],
//   m  = mt*16 + (lane&15)
//   ch = kt*16 + 64*(e>>2) + (lane>>4)*4 + (e&3)   (k-slot permutation)
// ---------------------------------------------------------------------------
__global__ void prep_w_kernel(const float* __restrict__ wff,
                              const float* __restrict__ wrec,
                              __bf16* __restrict__ wt,
                              __bf16* __restrict__ wrp) {
  int i = blockIdx.x * 256 + threadIdx.x;
  const int NW = 9 * COUT * CIN;            // 73728
  if (i < NW) {
    int tap = i / (COUT * CIN);
    int rem = i % (COUT * CIN);
    int o = rem >> 6;
    int c = rem & 63;
    int kh = tap / 3, kw = tap % 3;
    wt[i] = (__bf16)wff[((o * CIN + c) * 3 + kh) * 3 + kw];
  } else {
    int j = i - NW;                         // 0..16383
    if (j < 32 * 64 * 8) {
      int e    = j & 7;
      int lane = (j >> 3) & 63;
      int fk   = j >> 9;                    // mt*4 + kt
      int mt = fk >> 2, kt = fk & 3;
      int m    = mt * 16 + (lane & 15);
      int quad = lane >> 4;
      int ch   = kt * 16 + ((e >> 2) << 6) + quad * 4 + (e & 3);
      wrp[j] = (__bf16)(-wrec[m * COUT + ch]);
    }
  }
}

// ---------------------------------------------------------------------------
// prep_x: x NCHW fp32 -> bf16, layout [b][h][c>>3][w][c&7]
// ---------------------------------------------------------------------------
__global__ void prep_x_kernel(const float* __restrict__ x,
                              __bf16* __restrict__ xh) {
  __shared__ float t[64][65];
  int tid = threadIdx.x;
  int b = blockIdx.x >> 6;
  int h = blockIdx.x & 63;
#pragma unroll
  for (int it = 0; it < 16; ++it) {
    int c = it * 4 + (tid >> 6);
    int w = tid & 63;
    t[c][w] = x[(((size_t)(b * 64 + c)) * 64 + h) * 64 + w];
  }
  __syncthreads();
  size_t rowbase = (size_t)blockIdx.x * 4096;
#pragma unroll
  for (int it = 0; it < 16; ++it) {
    int j = it * 256 + tid;
    int c8  = j & 7;
    int w   = (j >> 3) & 63;
    int grp = j >> 9;
    xh[rowbase + j] = (__bf16)t[grp * 8 + c8][w];
  }
}

// ---------------------------------------------------------------------------
// conv: persistent-weight implicit GEMM, 32x32x16 bf16 MFMA.
// Wf (144 regs) pinned into AGPRs -> zero weight traffic in the nt loop.
// ---------------------------------------------------------------------------
__global__ __launch_bounds__(256, 2) void conv_kernel(
    const __bf16* __restrict__ xh, const __bf16* __restrict__ wt,
    float* __restrict__ u0) {
  // layout [row 6][grp 8][w 64][c8 8] = 24576 el = 48KB, flat == global order
  __shared__ __align__(16) __bf16 xs[6 * 8 * 64 * 8];
  int tid  = threadIdx.x;
  int lane = tid & 63;
  int wv   = tid >> 6;                      // 0..3 : c_out slice
  int hg   = blockIdx.x;                    // 0..15 : output-row group (4 rows)
  int b    = blockIdx.y;

  // ---- stage 6 input rows (hg*4 .. hg*4+5, clamped) ----
#pragma unroll
  for (int i = 0; i < 12; ++i) {
    int chunk = wv * 12 + i;                // 0..47
    int row = chunk >> 3;
    int part = chunk & 7;
    int row_src = hg * 4 + row;
    if (row_src > 63) row_src = 63;
    const __bf16* g = xh + ((size_t)(b * 64 + row_src)) * 4096 + part * 512 + lane * 8;
    __bf16* l = xs + chunk * 512;
    __builtin_amdgcn_global_load_lds(
        (const __attribute__((address_space(1))) void*)g,
        (__attribute__((address_space(3))) void*)l, 16, 0, 0);
  }

  // ---- this wave's full weight set -> AGPRs (loaded once, resident) ----
  int m31 = lane & 31;
  int khalf = lane >> 5;                    // A[m][k]: m=lane&31, k=khalf*8+j
  bf16x8 Wf[36];
#pragma unroll
  for (int tap = 0; tap < 9; ++tap)
#pragma unroll
    for (int k4 = 0; k4 < 4; ++k4)
      Wf[tap * 4 + k4] = *(const bf16x8*)
          &wt[((size_t)tap * COUT + wv * 32 + m31) * CIN + k4 * 16 + khalf * 8];
#pragma unroll
  for (int i = 0; i < 36; ++i) PIN_A(Wf[i]);

  __syncthreads();

  // ---- 8 n-tiles of 32 pixels ----
#pragma unroll 1
  for (int nt = 0; nt < 8; ++nt) {
    int px = nt * 32 + m31;                 // local pixel 0..255 (248 valid)
    int r = (px >= 62) + (px >= 124) + (px >= 186) + (px >= 248);
    if (r > 3) r = 3;
    int wcol = px - r * 62;
    if (wcol > 61) wcol = 61;
    int orow = hg * 4 + r;
    bool valid = (px < 248) && (orow < 62);
    const char* lbase = (const char*)xs + (((r * 8 + khalf) * 64 + wcol) << 4);

    f32x16 acc0, acc1;
#pragma unroll
    for (int q = 0; q < 16; ++q) { acc0[q] = 0.f; acc1[q] = 0.f; }

#pragma unroll
    for (int tap = 0; tap < 9; ++tap) {
      int kh = tap / 3, kw = tap % 3;
#pragma unroll
      for (int k4 = 0; k4 < 4; ++k4) {
        bf16x8 Bf = *(const bf16x8*)(lbase + kh * 8192 + k4 * 2048 + kw * 16);
        int idx = tap * 4 + k4;
        if (idx & 1) acc1 = __builtin_amdgcn_mfma_f32_32x32x16_bf16(Wf[idx], Bf, acc1, 0, 0, 0);
        else         acc0 = __builtin_amdgcn_mfma_f32_32x32x16_bf16(Wf[idx], Bf, acc0, 0, 0, 0);
      }
    }
    if (valid) {
      size_t pix = ((size_t)b * HO + orow) * WO + wcol;
      // C/D layout 32x32: col=lane&31, row=(reg&3)+8*(reg>>2)+4*khalf
      float* up = u0 + pix * COUT + wv * 32 + khalf * 4;
#pragma unroll
      for (int g4 = 0; g4 < 4; ++g4) {
        f32x4 v;
#pragma unroll
        for (int q = 0; q < 4; ++q) v[q] = acc0[g4 * 4 + q] + acc1[g4 * 4 + q];
        *(f32x4*)&up[g4 * 8] = v;
      }
    }
  }
}

// ---------------------------------------------------------------------------
// iterate: 11 undamped Picard matvecs. N=16 px/wave, 3 waves/SIMD.
// This is the R4 95-us kernel (confirmed at the per-CU ds_read_b128 issue
// ceiling: 12 waves x 32 reads x 12cyc x 11 iters) with ONE delta: 8 of the
// 32 A-fragments (mt 0..1) persist in AGPRs; only 24 stream from LDS
// (24 KB staged) -> 25% less of the binding resource.
// Ledger (registers, not fragments -- R6's error): AGPR = acc 32 + u0f 32
// + Afp 8x4 = 96; arch = R4-measured 64; total 160 <= 168 @ (256,3).
// R6 post-mortem: fused repack + 12-frag persist overflowed the 84-reg
// arch half (WRITE 127->207MB scratch). This keeps R4's exact loop body.
// Spill tripwire: FETCH/WRITE inflation next round -> drop to 4 frags.
// ---------------------------------------------------------------------------
__global__ __launch_bounds__(256, 3) void iterate_kernel(
    const float* __restrict__ u0, const __bf16* __restrict__ wrp,
    const float* __restrict__ thr, float* __restrict__ out) {
  __shared__ __align__(16) __bf16 wrl[24 * 64 * 8];   // frags fk=8..31, 24 KB
  int tid = threadIdx.x;
  int lane = tid & 63, wv = tid >> 6;
  int l15 = lane & 15, quad = lane >> 4;
  size_t p = (size_t)blockIdx.x * 64 + wv * 16 + l15; // this lane's pixel
  int pb = (int)(p / (HO * WO));            // batch  (for NCHW store)
  int pr = (int)(p % (HO * WO));            // h*62+w

  // ---- stage stream frags (fk 8..31) -> LDS, 6 x 16B per thread ----
#pragma unroll
  for (int i = 0; i < 6; ++i) {
    const __bf16* g = wrp + (size_t)8 * 512 + (size_t)(i * 256 + tid) * 8;
    __bf16* l = wrl + (i * 256 + tid) * 8;
    __builtin_amdgcn_global_load_lds(
        (const __attribute__((address_space(1))) void*)g,
        (__attribute__((address_space(3))) void*)l, 16, 0, 0);
  }

  // ---- persistent A-frags fk 0..7 (mt 0..1) -> AGPR (32 regs) ----
  bf16x8 Afp[8];
#pragma unroll
  for (int j = 0; j < 8; ++j)
    Afp[j] = *(const bf16x8*)&wrp[((size_t)j * 64 + lane) * 8];
#pragma unroll
  for (int j = 0; j < 8; ++j) PIN_A(Afp[j]);

  // u0 - thr fragments (C-layout) -> AGPR half
  f32x4 u0f[8];
#pragma unroll
  for (int mt = 0; mt < 8; ++mt) {
    f32x4 u = *(const f32x4*)&u0[p * COUT + mt * 16 + quad * 4];
    f32x4 t = *(const f32x4*)&thr[mt * 16 + quad * 4];
    u0f[mt] = u - t;
  }
#pragma unroll
  for (int mt = 0; mt < 8; ++mt) PIN_A(u0f[mt]);

  // acc starts as u0-thr so the first repack yields a_0 = relu(u0-thr)
  f32x4 acc[8];
#pragma unroll
  for (int mt = 0; mt < 8; ++mt) { acc[mt] = u0f[mt]; PIN_A(acc[mt]); }

  __syncthreads();                          // wrl ready (vmcnt drained here)

  const __bf16* afrag = &wrl[(size_t)lane * 8];   // + (fk-8)*1024B imm

  bf16x8 Bf[4];
#pragma unroll 1
  for (int it = 0; it < NITER; ++it) {
    // repack: B-slot (kt, q, e) <- relu(acc channel kt*16+64*(e>>2)+q*4+(e&3))
    //         = relu(acc[kt + 4*(e>>2)][e&3])   (purely lane-local)
#pragma unroll
    for (int kt = 0; kt < 4; ++kt) {
      bf16x8 v;
#pragma unroll
      for (int e = 0; e < 4; ++e) v[e]     = (__bf16)fmaxf(acc[kt][e],     0.f);
#pragma unroll
      for (int e = 0; e < 4; ++e) v[e + 4] = (__bf16)fmaxf(acc[kt + 4][e], 0.f);
      Bf[kt] = v;
    }
#pragma unroll
    for (int mt = 0; mt < 8; ++mt) {
      f32x4 a = u0f[mt];                    // acc init = u0-thr; Wr negated
#pragma unroll
      for (int kt = 0; kt < 4; ++kt) {
        bf16x8 Af;
        if (mt < 2) Af = Afp[mt * 4 + kt];  // static: loop fully unrolled
        else        Af = *(const bf16x8*)(afrag + (size_t)(mt * 4 + kt - 8) * 512);
        a = __builtin_amdgcn_mfma_f32_16x16x32_bf16(Af, Bf[kt], a, 0, 0, 0);
      }
      acc[mt] = a;
      PIN_A(acc[mt]);                       // keep in AGPR half across iters
    }
  }
  // final matvec -> relu -> NCHW global store
  {
#pragma unroll
    for (int kt = 0; kt < 4; ++kt) {
      bf16x8 v;
#pragma unroll
      for (int e = 0; e < 4; ++e) v[e]     = (__bf16)fmaxf(acc[kt][e],     0.f);
#pragma unroll
      for (int e = 0; e < 4; ++e) v[e + 4] = (__bf16)fmaxf(acc[kt + 4][e], 0.f);
      Bf[kt] = v;
    }
#pragma unroll
    for (int mt = 0; mt < 8; ++mt) {
      f32x4 a = u0f[mt];
#pragma unroll
      for (int kt = 0; kt < 4; ++kt) {
        bf16x8 Af;
        if (mt < 2) Af = Afp[mt * 4 + kt];
        else        Af = *(const bf16x8*)(afrag + (size_t)(mt * 4 + kt - 8) * 512);
        a = __builtin_amdgcn_mfma_f32_16x16x32_bf16(Af, Bf[kt], a, 0, 0, 0);
      }
#pragma unroll
      for (int r = 0; r < 4; ++r) {
        int ch = mt * 16 + quad * 4 + r;
        out[((size_t)pb * COUT + ch) * (HO * WO) + pr] = fmaxf(a[r], 0.f);
      }
    }
  }
}

// ---------------------------------------------------------------------------
extern "C" void kernel_launch(void* const* d_in, const int* in_sizes, int n_in,
                              void* d_out, int out_size, void* d_ws, size_t ws_size,
                              hipStream_t stream) {
  const float* x    = (const float*)d_in[0];   // (64,64,64,64)
  const float* wff  = (const float*)d_in[1];   // (128,64,3,3)
  const float* wrec = (const float*)d_in[2];   // (128,128,1,1)
  const float* thr  = (const float*)d_in[3];   // (128,)
  float* out = (float*)d_out;                  // (64,128,62,62)

  char* ws = (char*)d_ws;
  size_t off = 0;
  float*  u0 = (float*)(ws + off);  off += (size_t)NPIX * COUT * 4;          // 126 MB
  __bf16* xh = (__bf16*)(ws + off); off += (size_t)B_ * HIN * WIN * CIN * 2; // 33.6 MB
  __bf16* wt = (__bf16*)(ws + off); off += (size_t)9 * COUT * CIN * 2;       // 147 KB
  __bf16* wrp = (__bf16*)(ws + off); off += (size_t)32 * 64 * 8 * 2;         // 32 KB

  prep_w_kernel<<<352, 256, 0, stream>>>(wff, wrec, wt, wrp);
  prep_x_kernel<<<B_ * HIN, 256, 0, stream>>>(x, xh);
  conv_kernel<<<dim3(16, B_), 256, 0, stream>>>(xh, wt, u0);
  iterate_kernel<<<NPIX / 64, 256, 0, stream>>>(u0, wrp, thr, out);
}

// Round 8
// 321.659 us; speedup vs baseline: 1.1637x; 1.0099x over previous
//
#include <hip/hip_runtime.h>
#include <hip/hip_bf16.h>

typedef __bf16 bf16x8 __attribute__((ext_vector_type(8)));
typedef __bf16 bf16x4 __attribute__((ext_vector_type(4)));
typedef float  f32x4  __attribute__((ext_vector_type(4)));
typedef float  f32x16 __attribute__((ext_vector_type(16)));

#define B_    64
#define CIN   64
#define HIN   64
#define WIN   64
#define COUT  128
#define HO    62
#define WO    62
#define NPIX  (B_*HO*WO)        /* 246016 = 3844*64 exactly */
#define NITER 10                /* LDS rounds; +1 final matvec = 11 total */

// Register-file steering on the gfx950 unified VGPR/AGPR file.
#define PIN_A(x) asm volatile("" : "+a"(x))
#define PIN_V(x) asm volatile("" : "+v"(x))

// ---------------------------------------------------------------------------
// prep_w: W_ff -> wt[tap][o][c] bf16 ;
//         W_rec -> wrp: NEGATED, pre-permuted per-lane A-fragment table.
// wrp[((mt*4+kt)*64 + lane)*8 + e] = -wrec[m][ch],
//   m  = mt*16 + (lane&15)
//   ch = kt*16 + 64*(e>>2) + (lane>>4)*4 + (e&3)   (k-slot permutation)
// ---------------------------------------------------------------------------
__global__ void prep_w_kernel(const float* __restrict__ wff,
                              const float* __restrict__ wrec,
                              __bf16* __restrict__ wt,
                              __bf16* __restrict__ wrp) {
  int i = blockIdx.x * 256 + threadIdx.x;
  const int NW = 9 * COUT * CIN;            // 73728
  if (i < NW) {
    int tap = i / (COUT * CIN);
    int rem = i % (COUT * CIN);
    int o = rem >> 6;
    int c = rem & 63;
    int kh = tap / 3, kw = tap % 3;
    wt[i] = (__bf16)wff[((o * CIN + c) * 3 + kh) * 3 + kw];
  } else {
    int j = i - NW;                         // 0..16383
    if (j < 32 * 64 * 8) {
      int e    = j & 7;
      int lane = (j >> 3) & 63;
      int fk   = j >> 9;                    // mt*4 + kt
      int mt = fk >> 2, kt = fk & 3;
      int m    = mt * 16 + (lane & 15);
      int quad = lane >> 4;
      int ch   = kt * 16 + ((e >> 2) << 6) + quad * 4 + (e & 3);
      wrp[j] = (__bf16)(-wrec[m * COUT + ch]);
    }
  }
}

// ---------------------------------------------------------------------------
// prep_x: x NCHW fp32 -> bf16, layout [b][h][c>>3][w][c&7].
// R8: no LDS round-trip, no scalar bf16 stores. Thread owns (grp,w) pairs:
// reads 8 channels as fully-coalesced f32 (for fixed c, lanes are
// contiguous in w), packs bf16x8, ONE 16-B store (lane-stride 16B = 1KB
// per wave-store, perfectly coalesced). Old version: 16 scalar 2-byte
// global stores/thread (quarter-rate) + 32 LDS ops.
// ---------------------------------------------------------------------------
__global__ void prep_x_kernel(const float* __restrict__ x,
                              __bf16* __restrict__ xh) {
  int tid = threadIdx.x;
  int b = blockIdx.x >> 6;
  int h = blockIdx.x & 63;
  size_t rowbase = (size_t)blockIdx.x * 4096;
#pragma unroll
  for (int it = 0; it < 2; ++it) {
    int pi  = it * 256 + tid;               // 0..511 : (grp, w)
    int grp = pi >> 6;
    int w   = pi & 63;
    bf16x8 v;
#pragma unroll
    for (int c8 = 0; c8 < 8; ++c8) {
      int c = grp * 8 + c8;
      v[c8] = (__bf16)x[(((size_t)(b * 64 + c)) * 64 + h) * 64 + w];
    }
    *(bf16x8*)&xh[rowbase + grp * 512 + w * 8] = v;
  }
}

// ---------------------------------------------------------------------------
// conv: persistent-weight implicit GEMM, 32x32x16 bf16 MFMA.
// Wf (144 regs) pinned into AGPRs -> zero weight traffic in the nt loop.
// ---------------------------------------------------------------------------
__global__ __launch_bounds__(256, 2) void conv_kernel(
    const __bf16* __restrict__ xh, const __bf16* __restrict__ wt,
    float* __restrict__ u0) {
  // layout [row 6][grp 8][w 64][c8 8] = 24576 el = 48KB, flat == global order
  __shared__ __align__(16) __bf16 xs[6 * 8 * 64 * 8];
  int tid  = threadIdx.x;
  int lane = tid & 63;
  int wv   = tid >> 6;                      // 0..3 : c_out slice
  int hg   = blockIdx.x;                    // 0..15 : output-row group (4 rows)
  int b    = blockIdx.y;

  // ---- stage 6 input rows (hg*4 .. hg*4+5, clamped) ----
#pragma unroll
  for (int i = 0; i < 12; ++i) {
    int chunk = wv * 12 + i;                // 0..47
    int row = chunk >> 3;
    int part = chunk & 7;
    int row_src = hg * 4 + row;
    if (row_src > 63) row_src = 63;
    const __bf16* g = xh + ((size_t)(b * 64 + row_src)) * 4096 + part * 512 + lane * 8;
    __bf16* l = xs + chunk * 512;
    __builtin_amdgcn_global_load_lds(
        (const __attribute__((address_space(1))) void*)g,
        (__attribute__((address_space(3))) void*)l, 16, 0, 0);
  }

  // ---- this wave's full weight set -> AGPRs (loaded once, resident) ----
  int m31 = lane & 31;
  int khalf = lane >> 5;                    // A[m][k]: m=lane&31, k=khalf*8+j
  bf16x8 Wf[36];
#pragma unroll
  for (int tap = 0; tap < 9; ++tap)
#pragma unroll
    for (int k4 = 0; k4 < 4; ++k4)
      Wf[tap * 4 + k4] = *(const bf16x8*)
          &wt[((size_t)tap * COUT + wv * 32 + m31) * CIN + k4 * 16 + khalf * 8];
#pragma unroll
  for (int i = 0; i < 36; ++i) PIN_A(Wf[i]);

  __syncthreads();

  // ---- 8 n-tiles of 32 pixels ----
#pragma unroll 1
  for (int nt = 0; nt < 8; ++nt) {
    int px = nt * 32 + m31;                 // local pixel 0..255 (248 valid)
    int r = (px >= 62) + (px >= 124) + (px >= 186) + (px >= 248);
    if (r > 3) r = 3;
    int wcol = px - r * 62;
    if (wcol > 61) wcol = 61;
    int orow = hg * 4 + r;
    bool valid = (px < 248) && (orow < 62);
    const char* lbase = (const char*)xs + (((r * 8 + khalf) * 64 + wcol) << 4);

    f32x16 acc0, acc1;
#pragma unroll
    for (int q = 0; q < 16; ++q) { acc0[q] = 0.f; acc1[q] = 0.f; }

#pragma unroll
    for (int tap = 0; tap < 9; ++tap) {
      int kh = tap / 3, kw = tap % 3;
#pragma unroll
      for (int k4 = 0; k4 < 4; ++k4) {
        bf16x8 Bf = *(const bf16x8*)(lbase + kh * 8192 + k4 * 2048 + kw * 16);
        int idx = tap * 4 + k4;
        if (idx & 1) acc1 = __builtin_amdgcn_mfma_f32_32x32x16_bf16(Wf[idx], Bf, acc1, 0, 0, 0);
        else         acc0 = __builtin_amdgcn_mfma_f32_32x32x16_bf16(Wf[idx], Bf, acc0, 0, 0, 0);
      }
    }
    if (valid) {
      size_t pix = ((size_t)b * HO + orow) * WO + wcol;
      // C/D layout 32x32: col=lane&31, row=(reg&3)+8*(reg>>2)+4*khalf
      float* up = u0 + pix * COUT + wv * 32 + khalf * 4;
#pragma unroll
      for (int g4 = 0; g4 < 4; ++g4) {
        f32x4 v;
#pragma unroll
        for (int q = 0; q < 4; ++q) v[q] = acc0[g4 * 4 + q] + acc1[g4 * 4 + q];
        *(f32x4*)&up[g4 * 8] = v;
      }
    }
  }
}

// ---------------------------------------------------------------------------
// iterate: 11 undamped Picard matvecs. N=16 px/wave, targeting 3 waves/SIMD.
// R7 post-mortem: Afp=8 put AGPR demand at 96 > the 84-reg AGPR half at
// (256,3) -> HW fell to ~2 waves/SIMD (Occupancy 27%), cancelling the
// 32->24 read reduction (95us, same as R4). Hard wall: AGPR <= 84.
// R8: Afp=4 frags (mt=0): AGPR = acc 32 + u0f 32 + Afp 16 = 80 <= 84,
// reads 28/iter streamed from 28 KB LDS. Per-CU read-issue model:
// 15 blk x 4 wv x 11 it x 28 rd x 12 cyc = 222k cyc ~ 92us x 0.9 eff.
// Tripwire: Occupancy < 30% or WRITE > 140 MB -> AGPR overflow, revert.
// ---------------------------------------------------------------------------
__global__ __launch_bounds__(256, 3) void iterate_kernel(
    const float* __restrict__ u0, const __bf16* __restrict__ wrp,
    const float* __restrict__ thr, float* __restrict__ out) {
  __shared__ __align__(16) __bf16 wrl[28 * 64 * 8];   // frags fk=4..31, 28 KB
  int tid = threadIdx.x;
  int lane = tid & 63, wv = tid >> 6;
  int l15 = lane & 15, quad = lane >> 4;
  size_t p = (size_t)blockIdx.x * 64 + wv * 16 + l15; // this lane's pixel
  int pb = (int)(p / (HO * WO));            // batch  (for NCHW store)
  int pr = (int)(p % (HO * WO));            // h*62+w

  // ---- stage stream frags (fk 4..31) -> LDS, 7 x 16B per thread ----
#pragma unroll
  for (int i = 0; i < 7; ++i) {
    const __bf16* g = wrp + (size_t)4 * 512 + (size_t)(i * 256 + tid) * 8;
    __bf16* l = wrl + (i * 256 + tid) * 8;
    __builtin_amdgcn_global_load_lds(
        (const __attribute__((address_space(1))) void*)g,
        (__attribute__((address_space(3))) void*)l, 16, 0, 0);
  }

  // ---- persistent A-frags fk 0..3 (mt 0) -> AGPR (16 regs) ----
  bf16x8 Afp[4];
#pragma unroll
  for (int j = 0; j < 4; ++j)
    Afp[j] = *(const bf16x8*)&wrp[((size_t)j * 64 + lane) * 8];
#pragma unroll
  for (int j = 0; j < 4; ++j) PIN_A(Afp[j]);

  // u0 - thr fragments (C-layout) -> AGPR half
  f32x4 u0f[8];
#pragma unroll
  for (int mt = 0; mt < 8; ++mt) {
    f32x4 u = *(const f32x4*)&u0[p * COUT + mt * 16 + quad * 4];
    f32x4 t = *(const f32x4*)&thr[mt * 16 + quad * 4];
    u0f[mt] = u - t;
  }
#pragma unroll
  for (int mt = 0; mt < 8; ++mt) PIN_A(u0f[mt]);

  // acc starts as u0-thr so the first repack yields a_0 = relu(u0-thr)
  f32x4 acc[8];
#pragma unroll
  for (int mt = 0; mt < 8; ++mt) { acc[mt] = u0f[mt]; PIN_A(acc[mt]); }

  __syncthreads();                          // wrl ready (vmcnt drained here)

  const __bf16* afrag = &wrl[(size_t)lane * 8];   // + (fk-4)*1024B imm

  bf16x8 Bf[4];
#pragma unroll 1
  for (int it = 0; it < NITER; ++it) {
    // repack: B-slot (kt, q, e) <- relu(acc channel kt*16+64*(e>>2)+q*4+(e&3))
    //         = relu(acc[kt + 4*(e>>2)][e&3])   (purely lane-local)
#pragma unroll
    for (int kt = 0; kt < 4; ++kt) {
      bf16x8 v;
#pragma unroll
      for (int e = 0; e < 4; ++e) v[e]     = (__bf16)fmaxf(acc[kt][e],     0.f);
#pragma unroll
      for (int e = 0; e < 4; ++e) v[e + 4] = (__bf16)fmaxf(acc[kt + 4][e], 0.f);
      Bf[kt] = v;
    }
#pragma unroll
    for (int mt = 0; mt < 8; ++mt) {
      f32x4 a = u0f[mt];                    // acc init = u0-thr; Wr negated
#pragma unroll
      for (int kt = 0; kt < 4; ++kt) {
        bf16x8 Af;
        if (mt < 1) Af = Afp[kt];           // static: loop fully unrolled
        else        Af = *(const bf16x8*)(afrag + (size_t)(mt * 4 + kt - 4) * 512);
        a = __builtin_amdgcn_mfma_f32_16x16x32_bf16(Af, Bf[kt], a, 0, 0, 0);
      }
      acc[mt] = a;
      PIN_A(acc[mt]);                       // keep in AGPR half across iters
    }
  }
  // final matvec -> relu -> NCHW global store
  {
#pragma unroll
    for (int kt = 0; kt < 4; ++kt) {
      bf16x8 v;
#pragma unroll
      for (int e = 0; e < 4; ++e) v[e]     = (__bf16)fmaxf(acc[kt][e],     0.f);
#pragma unroll
      for (int e = 0; e < 4; ++e) v[e + 4] = (__bf16)fmaxf(acc[kt + 4][e], 0.f);
      Bf[kt] = v;
    }
#pragma unroll
    for (int mt = 0; mt < 8; ++mt) {
      f32x4 a = u0f[mt];
#pragma unroll
      for (int kt = 0; kt < 4; ++kt) {
        bf16x8 Af;
        if (mt < 1) Af = Afp[kt];
        else        Af = *(const bf16x8*)(afrag + (size_t)(mt * 4 + kt - 4) * 512);
        a = __builtin_amdgcn_mfma_f32_16x16x32_bf16(Af, Bf[kt], a, 0, 0, 0);
      }
#pragma unroll
      for (int r = 0; r < 4; ++r) {
        int ch = mt * 16 + quad * 4 + r;
        out[((size_t)pb * COUT + ch) * (HO * WO) + pr] = fmaxf(a[r], 0.f);
      }
    }
  }
}

// ---------------------------------------------------------------------------
extern "C" void kernel_launch(void* const* d_in, const int* in_sizes, int n_in,
                              void* d_out, int out_size, void* d_ws, size_t ws_size,
                              hipStream_t stream) {
  const float* x    = (const float*)d_in[0];   // (64,64,64,64)
  const float* wff  = (const float*)d_in[1];   // (128,64,3,3)
  const float* wrec = (const float*)d_in[2];   // (128,128,1,1)
  const float* thr  = (const float*)d_in[3];   // (128,)
  float* out = (float*)d_out;                  // (64,128,62,62)

  char* ws = (char*)d_ws;
  size_t off = 0;
  float*  u0 = (float*)(ws + off);  off += (size_t)NPIX * COUT * 4;          // 126 MB
  __bf16* xh = (__bf16*)(ws + off); off += (size_t)B_ * HIN * WIN * CIN * 2; // 33.6 MB
  __bf16* wt = (__bf16*)(ws + off); off += (size_t)9 * COUT * CIN * 2;       // 147 KB
  __bf16* wrp = (__bf16*)(ws + off); off += (size_t)32 * 64 * 8 * 2;         // 32 KB

  prep_w_kernel<<<352, 256, 0, stream>>>(wff, wrec, wt, wrp);
  prep_x_kernel<<<B_ * HIN, 256, 0, stream>>>(x, xh);
  conv_kernel<<<dim3(16, B_), 256, 0, stream>>>(xh, wt, u0);
  iterate_kernel<<<NPIX / 64, 256, 0, stream>>>(u0, wrp, thr, out);
}